// Round 1
// 4454.157 us; speedup vs baseline: 1.9753x; 1.9753x over previous
//
#include <hip/hip_runtime.h>
#include <hip/hip_bf16.h>

// ---------------------------------------------------------------------------
// GPT-2 small forward: B=4 S=1024 L=12 D=768 H=12 DK=64 DFF=3072 V=50257
// Round 1 of polish: all-bf16 GEMM operands (one-time transpose/convert of
// weights to [N,K]), m97-structure GEMM with global_load_lds dwordx4 staging,
// fused QKV GEMM, bf16 activations between GEMMs, fp32 residual stream.
// ---------------------------------------------------------------------------

typedef __bf16 bf16;
typedef bf16 bf16x8 __attribute__((ext_vector_type(8)));
typedef bf16 bf16x4 __attribute__((ext_vector_type(4)));
typedef float f32x4 __attribute__((ext_vector_type(4)));

#define MFMA_BF16(a, b, c) __builtin_amdgcn_mfma_f32_16x16x32_bf16((a), (b), (c), 0, 0, 0)

#define NTOK 4096
#define DIM 768
#define DFF_ 3072
#define NHEAD 12
#define DK_ 64
#define SEQ 1024
#define VOCAB 50257
#define VPAD 50304      // 393 * 128
#define NLAYER 12
#define QKVD 2304

__device__ __forceinline__ float gelu_exact(float v) {
    return 0.5f * v * (1.0f + erff(v * 0.70710678118654752f));
}

// async global->LDS 16B (dest = wave-uniform base + lane*16; our lane->chunk
// mapping is linear so per-lane pointers are consistent with HW semantics)
__device__ __forceinline__ void gload16(const bf16* g, bf16* l) {
    __builtin_amdgcn_global_load_lds(
        (const __attribute__((address_space(1))) void*)g,
        (__attribute__((address_space(3))) void*)l, 16, 0, 0);
}

// ---------------------------------------------------------------------------
// Embedding: x[n,:] = wte[idx[n],:] + wpe[n % S,:]   (fp32 residual stream)
// ---------------------------------------------------------------------------
__global__ __launch_bounds__(256) void embed_kernel(const int* __restrict__ idx,
                                                    const float* __restrict__ wte,
                                                    const float* __restrict__ wpe,
                                                    float* __restrict__ x) {
    int n = blockIdx.x;
    int t = idx[n];
    int s = n & (SEQ - 1);
    size_t xo = (size_t)n * DIM;
    size_t to = (size_t)t * DIM;
    size_t so = (size_t)s * DIM;
    for (int d = threadIdx.x; d < DIM; d += 256)
        x[xo + d] = wte[to + d] + wpe[so + d];
}

// ---------------------------------------------------------------------------
// LayerNorm fp32 -> bf16 out: one block (256 threads) per token, D=768
// ---------------------------------------------------------------------------
__global__ __launch_bounds__(256) void ln_kernel(const float* __restrict__ in,
                                                 bf16* __restrict__ out,
                                                 const float* __restrict__ w,
                                                 const float* __restrict__ b) {
    int n = blockIdx.x;
    int tid = threadIdx.x;
    const float* row = in + (size_t)n * DIM;
    float x0 = row[tid], x1 = row[tid + 256], x2 = row[tid + 512];
    float s = x0 + x1 + x2;
    float sq = x0 * x0 + x1 * x1 + x2 * x2;
#pragma unroll
    for (int off = 32; off > 0; off >>= 1) {
        s += __shfl_down(s, off);
        sq += __shfl_down(sq, off);
    }
    __shared__ float sw[4], sqw[4];
    int wv = tid >> 6;
    if ((tid & 63) == 0) { sw[wv] = s; sqw[wv] = sq; }
    __syncthreads();
    s = sw[0] + sw[1] + sw[2] + sw[3];
    sq = sqw[0] + sqw[1] + sqw[2] + sqw[3];
    float mean = s * (1.0f / 768.0f);
    float var = sq * (1.0f / 768.0f) - mean * mean;
    float inv = rsqrtf(var + 1e-5f);
    bf16* orow = out + (size_t)n * DIM;
    orow[tid]       = (bf16)((x0 - mean) * inv * w[tid]       + b[tid]);
    orow[tid + 256] = (bf16)((x1 - mean) * inv * w[tid + 256] + b[tid + 256]);
    orow[tid + 512] = (bf16)((x2 - mean) * inv * w[tid + 512] + b[tid + 512]);
}

// ---------------------------------------------------------------------------
// wte fp32 [V,D] -> bf16 [VPAD,D] (already [N,K] for the tied head; pad rows
// zeroed). Grid covers VPAD*DIM/4/256 = 37728 blocks exactly.
// ---------------------------------------------------------------------------
__global__ __launch_bounds__(256) void cvt_wte_kernel(const float* __restrict__ wte,
                                                      bf16* __restrict__ o) {
    size_t i = ((size_t)blockIdx.x * 256 + threadIdx.x) * 4;
    size_t row = i / DIM;
    bf16x4 t;
    if (row < VOCAB) {
        float4 v = *(const float4*)&wte[i];
        t[0] = (bf16)v.x; t[1] = (bf16)v.y; t[2] = (bf16)v.z; t[3] = (bf16)v.w;
    } else {
        t[0] = t[1] = t[2] = t[3] = (bf16)0.f;
    }
    *(bf16x4*)&o[i] = t;
}

// ---------------------------------------------------------------------------
// Per-layer weight transpose+convert to bf16 [N,K]:
//  blocks 0..1727   : wq/wk/wv [768,768] -> wqkv_t [2304,768]
//  blocks 1728..2303: wo       [768,768] -> wo_t   [768,768]
//  blocks 2304..4607: fc1      [768,3072]-> fc1_t  [3072,768]
//  blocks 4608..6911: fc2      [3072,768]-> fc2_t  [768,3072]
// 32x32 tile transpose per block, 256 threads (32x8).
// ---------------------------------------------------------------------------
__global__ __launch_bounds__(256) void cvt_layer_kernel(const float* __restrict__ wq,
                                                        const float* __restrict__ wk,
                                                        const float* __restrict__ wv,
                                                        const float* __restrict__ wo,
                                                        const float* __restrict__ f1,
                                                        const float* __restrict__ f2,
                                                        bf16* __restrict__ qkv_t,
                                                        bf16* __restrict__ wo_t,
                                                        bf16* __restrict__ fc1_t,
                                                        bf16* __restrict__ fc2_t) {
    int bid = blockIdx.x;
    const float* src;
    bf16* dst;
    int srcN, dstK, kb, nb;
    if (bid < 1728) {
        int w = bid / 576, t = bid % 576;
        src = (w == 0) ? wq : ((w == 1) ? wk : wv);
        srcN = 768; dstK = 768;
        nb = (t % 24) * 32; kb = (t / 24) * 32;
        dst = qkv_t + (size_t)w * 768 * 768;
    } else if (bid < 2304) {
        int t = bid - 1728;
        src = wo; srcN = 768; dstK = 768;
        nb = (t % 24) * 32; kb = (t / 24) * 32;
        dst = wo_t;
    } else if (bid < 4608) {
        int t = bid - 2304;
        src = f1; srcN = 3072; dstK = 768;
        nb = (t % 96) * 32; kb = (t / 96) * 32;
        dst = fc1_t;
    } else {
        int t = bid - 4608;
        src = f2; srcN = 768; dstK = 3072;
        nb = (t % 24) * 32; kb = (t / 24) * 32;
        dst = fc2_t;
    }
    __shared__ float tl[32][33];
    int tx = threadIdx.x & 31, ty = threadIdx.x >> 5;
#pragma unroll
    for (int i = 0; i < 32; i += 8)
        tl[ty + i][tx] = src[(size_t)(kb + ty + i) * srcN + nb + tx];
    __syncthreads();
#pragma unroll
    for (int i = 0; i < 32; i += 8)
        dst[(size_t)(nb + ty + i) * dstK + kb + tx] = (bf16)tl[tx][ty + i];
}

// ---------------------------------------------------------------------------
// bf16 MFMA GEMM (m97 structure): C[M,Nc] = A[M,K] @ Bt[Nb,K]^T
// A bf16 [M,K], Bt bf16 [Nb,K] with Nb = gridDim.y*128 (pre-padded).
// 128x128 tile, BK=32, linear LDS, global_load_lds dwordx4 staging.
// 256 threads = 4 waves (2x2), each wave 64x64 = 4x4 mfma_f32_16x16x32_bf16.
// EPI: 0 plain, 1 +R residual (fp32), 2 exact GELU. OUTBF: bf16 C.
// GUARD: guard C columns >= Nc (head, Nc=50257 < Nb=50304).
// ---------------------------------------------------------------------------
template <int EPI, bool OUTBF, bool GUARD>
__global__ __launch_bounds__(256) void gemm_bf_kernel(const bf16* __restrict__ A,
                                                      const bf16* __restrict__ Bt,
                                                      const float* __restrict__ R,
                                                      void* __restrict__ Cv,
                                                      int M, int Nc, int K) {
    (void)M;
    __shared__ __align__(16) bf16 As[128 * 32];
    __shared__ __align__(16) bf16 Bs[128 * 32];
    const int m0 = blockIdx.x * 128;
    const int n0 = blockIdx.y * 128;
    const int tid = threadIdx.x;
    const int lane = tid & 63;
    const int wave = tid >> 6;
    const int wm = (wave >> 1) * 64;
    const int wn = (wave & 1) * 64;
    const int quad = lane >> 4;
    const int r16 = lane & 15;

    f32x4 acc[4][4] = {};

    for (int k0 = 0; k0 < K; k0 += 32) {
        // stage A,B tiles [128 x 32] bf16 via async global->LDS, 16B/lane
#pragma unroll
        for (int i = 0; i < 2; i++) {
            int chunk = i * 256 + tid;          // 0..511
            int row = chunk >> 2;               // 0..127
            int col = (chunk & 3) * 8;          // 0,8,16,24
            gload16(&A[(size_t)(m0 + row) * K + k0 + col], &As[chunk * 8]);
            gload16(&Bt[(size_t)(n0 + row) * K + k0 + col], &Bs[chunk * 8]);
        }
        __syncthreads();
        bf16x8 af[4], bfr[4];
#pragma unroll
        for (int t = 0; t < 4; t++) {
            af[t]  = *(const bf16x8*)&As[(wm + t * 16 + r16) * 32 + quad * 8];
            bfr[t] = *(const bf16x8*)&Bs[(wn + t * 16 + r16) * 32 + quad * 8];
        }
#pragma unroll
        for (int tm = 0; tm < 4; tm++)
#pragma unroll
            for (int tn = 0; tn < 4; tn++)
                acc[tm][tn] = MFMA_BF16(af[tm], bfr[tn], acc[tm][tn]);
        __syncthreads();
    }

    // epilogue: C row = quad*4+i, col = r16 within each 16x16 tile
#pragma unroll
    for (int tm = 0; tm < 4; tm++) {
        int rb_ = m0 + wm + tm * 16 + quad * 4;
#pragma unroll
        for (int tn = 0; tn < 4; tn++) {
            int col = n0 + wn + tn * 16 + r16;
            if (GUARD && col >= Nc) continue;
#pragma unroll
            for (int i = 0; i < 4; i++) {
                size_t off = (size_t)(rb_ + i) * Nc + col;
                float v = acc[tm][tn][i];
                if constexpr (EPI == 1) v += R[off];
                if constexpr (EPI == 2) v = gelu_exact(v);
                if constexpr (OUTBF) ((bf16*)Cv)[off] = (bf16)v;
                else                 ((float*)Cv)[off] = v;
            }
        }
    }
}

// ---------------------------------------------------------------------------
// Flash attention: block per (qtile=64 rows, head, batch). 256 threads.
// q,k,v bf16 in fused qkv buffer [4096, 2304], head h at cols h*64 (+component
// offset baked into the pointer). Online softmax fp32; QK^T / PV bf16 MFMA.
// O written bf16 [4096, 768].
// ---------------------------------------------------------------------------
__global__ __launch_bounds__(256) void attn_kernel(const bf16* __restrict__ Qm,
                                                   const bf16* __restrict__ Km,
                                                   const bf16* __restrict__ Vm,
                                                   bf16* __restrict__ Om) {
    const int qt = blockIdx.x;  // 0..15
    const int h  = blockIdx.y;  // 0..11
    const int b  = blockIdx.z;  // 0..3
    const int tid = threadIdx.x;
    const int lane = tid & 63;
    const int wave = tid >> 6;
    const int quad = lane >> 4;
    const int r16 = lane & 15;
    const size_t qbase = (size_t)b * SEQ * QKVD + h * DK_;
    const size_t obase = (size_t)b * SEQ * DIM + h * DK_;

    __shared__ __align__(16) bf16 Qs[64][72];
    __shared__ __align__(16) bf16 Ks[64][72];
    __shared__ __align__(16) bf16 VsT[64][72]; // [d][kv] so PV B-frag is contiguous
    __shared__ __align__(16) bf16 Ps[64][72];
    __shared__ float Sc[64][66];
    __shared__ float pm[64][4], psum[64][4];
    __shared__ float mstate[64], lstate[64], alphas[64];

    // stage Q tile [64 x 64]
    {
        int r = tid >> 2, c0 = (tid & 3) * 16;
        const bf16* qrow = Qm + qbase + (size_t)(qt * 64 + r) * QKVD;
        *(bf16x8*)&Qs[r][c0]     = *(const bf16x8*)&qrow[c0];
        *(bf16x8*)&Qs[r][c0 + 8] = *(const bf16x8*)&qrow[c0 + 8];
    }
    if (tid < 64) { mstate[tid] = -1e30f; lstate[tid] = 0.f; }
    f32x4 accO[4] = {};
    __syncthreads();

    for (int j = 0; j <= qt; j++) {
        // stage K, V tiles
        {
            int r = tid >> 2, c0 = (tid & 3) * 16;
            const bf16* krow = Km + qbase + (size_t)(j * 64 + r) * QKVD;
            const bf16* vrow = Vm + qbase + (size_t)(j * 64 + r) * QKVD;
            *(bf16x8*)&Ks[r][c0]     = *(const bf16x8*)&krow[c0];
            *(bf16x8*)&Ks[r][c0 + 8] = *(const bf16x8*)&krow[c0 + 8];
            bf16x8 v0 = *(const bf16x8*)&vrow[c0];
            bf16x8 v1 = *(const bf16x8*)&vrow[c0 + 8];
#pragma unroll
            for (int i2 = 0; i2 < 8; i2++) {
                VsT[c0 + i2][r]     = v0[i2];
                VsT[c0 + 8 + i2][r] = v1[i2];
            }
        }
        __syncthreads();

        // scores: wave w handles q rows w*16..w*16+15, all 64 k cols
        bf16x8 qa0 = *(const bf16x8*)&Qs[wave * 16 + r16][quad * 8];
        bf16x8 qa1 = *(const bf16x8*)&Qs[wave * 16 + r16][32 + quad * 8];
#pragma unroll
        for (int t = 0; t < 4; t++) {
            f32x4 sc = {};
            bf16x8 kb0 = *(const bf16x8*)&Ks[t * 16 + r16][quad * 8];
            sc = MFMA_BF16(qa0, kb0, sc);
            bf16x8 kb1 = *(const bf16x8*)&Ks[t * 16 + r16][32 + quad * 8];
            sc = MFMA_BF16(qa1, kb1, sc);
            int kcol = t * 16 + r16;
            int gk = j * 64 + kcol;
#pragma unroll
            for (int i = 0; i < 4; i++) {
                int row = wave * 16 + quad * 4 + i;
                int gq = qt * 64 + row;
                Sc[row][kcol] = (gk <= gq) ? sc[i] * 0.125f : -1e30f;
            }
        }
        __syncthreads();

        // partial max (4 threads per row, 16 cols each)
        {
            int r = tid >> 2, p0 = (tid & 3) * 16;
            float mx = -1e30f;
#pragma unroll
            for (int c = 0; c < 16; c++) mx = fmaxf(mx, Sc[r][p0 + c]);
            pm[r][tid & 3] = mx;
        }
        __syncthreads();
        if (tid < 64) {
            float mnew = fmaxf(fmaxf(pm[tid][0], pm[tid][1]), fmaxf(pm[tid][2], pm[tid][3]));
            mnew = fmaxf(mnew, mstate[tid]);
            alphas[tid] = __expf(mstate[tid] - mnew);
            mstate[tid] = mnew;
        }
        __syncthreads();
        // exp + partial sums + P (bf16)
        {
            int r = tid >> 2, p0 = (tid & 3) * 16;
            float mnew = mstate[r];
            float sum = 0.f;
#pragma unroll
            for (int c = 0; c < 16; c++) {
                float p = __expf(Sc[r][p0 + c] - mnew);
                sum += p;
                Ps[r][p0 + c] = (bf16)p;
            }
            psum[r][tid & 3] = sum;
        }
        __syncthreads();
        if (tid < 64)
            lstate[tid] = lstate[tid] * alphas[tid] +
                          psum[tid][0] + psum[tid][1] + psum[tid][2] + psum[tid][3];
        // rescale O and accumulate PV
        float al[4];
#pragma unroll
        for (int i = 0; i < 4; i++) al[i] = alphas[wave * 16 + quad * 4 + i];
#pragma unroll
        for (int t = 0; t < 4; t++)
#pragma unroll
            for (int i = 0; i < 4; i++) accO[t][i] *= al[i];
#pragma unroll
        for (int kk = 0; kk < 2; kk++) {
            bf16x8 pa = *(const bf16x8*)&Ps[wave * 16 + r16][kk * 32 + quad * 8];
#pragma unroll
            for (int t = 0; t < 4; t++) {
                bf16x8 vb = *(const bf16x8*)&VsT[t * 16 + r16][kk * 32 + quad * 8];
                accO[t] = MFMA_BF16(pa, vb, accO[t]);
            }
        }
        __syncthreads();
    }

    // write O (bf16)
    float linv[4];
#pragma unroll
    for (int i = 0; i < 4; i++) linv[i] = 1.0f / lstate[wave * 16 + quad * 4 + i];
#pragma unroll
    for (int t = 0; t < 4; t++) {
        int col = t * 16 + r16;
#pragma unroll
        for (int i = 0; i < 4; i++) {
            int row = qt * 64 + wave * 16 + quad * 4 + i;
            Om[obase + (size_t)row * DIM + col] = (bf16)(accO[t][i] * linv[i]);
        }
    }
}

// ---------------------------------------------------------------------------
extern "C" void kernel_launch(void* const* d_in, const int* in_sizes, int n_in,
                              void* d_out, int out_size, void* d_ws, size_t ws_size,
                              hipStream_t stream) {
    (void)in_sizes; (void)n_in; (void)out_size; (void)ws_size;
    const int*   idx  = (const int*)d_in[0];
    const float* wte  = (const float*)d_in[1];
    const float* wpe  = (const float*)d_in[2];
    const float* ln1w = (const float*)d_in[3];
    const float* ln1b = (const float*)d_in[4];
    const float* wq   = (const float*)d_in[5];
    const float* wk   = (const float*)d_in[6];
    const float* wv   = (const float*)d_in[7];
    const float* wo   = (const float*)d_in[8];
    const float* ln2w = (const float*)d_in[9];
    const float* ln2b = (const float*)d_in[10];
    const float* fc1  = (const float*)d_in[11];
    const float* fc2  = (const float*)d_in[12];
    const float* lnfw = (const float*)d_in[13];
    const float* lnfb = (const float*)d_in[14];
    float* out = (float*)d_out;

    // workspace layout (all 16B aligned): ~142 MB total
    char* p = (char*)d_ws;
    float* x   = (float*)p; p += (size_t)NTOK * DIM * sizeof(float);   // 12.6 MB
    bf16* hb   = (bf16*)p;  p += (size_t)NTOK * DIM * 2;               // 6.3 MB
    bf16* qkv  = (bf16*)p;                                             // qkv / u union
    bf16* u    = qkv;       p += (size_t)NTOK * DFF_ * 2;              // 25.2 MB
    bf16* ao   = (bf16*)p;  p += (size_t)NTOK * DIM * 2;               // 6.3 MB
    bf16* wqkv_t = (bf16*)p; p += (size_t)QKVD * DIM * 2;              // 3.5 MB
    bf16* wo_t   = (bf16*)p; p += (size_t)DIM * DIM * 2;               // 1.2 MB
    bf16* fc1_t  = (bf16*)p; p += (size_t)DFF_ * DIM * 2;              // 4.7 MB
    bf16* fc2_t  = (bf16*)p; p += (size_t)DIM * DFF_ * 2;              // 4.7 MB
    bf16* wteb   = (bf16*)p; p += (size_t)VPAD * DIM * 2;              // 77.3 MB

    embed_kernel<<<NTOK, 256, 0, stream>>>(idx, wte, wpe, x);
    cvt_wte_kernel<<<(VPAD * DIM) / 1024, 256, 0, stream>>>(wte, wteb);

    for (int l = 0; l < NLAYER; l++) {
        const size_t DD = (size_t)DIM * DIM;
        const size_t DF = (size_t)DIM * DFF_;
        cvt_layer_kernel<<<6912, 256, 0, stream>>>(wq + l * DD, wk + l * DD, wv + l * DD,
                                                   wo + l * DD, fc1 + l * DF, fc2 + l * DF,
                                                   wqkv_t, wo_t, fc1_t, fc2_t);
        ln_kernel<<<NTOK, 256, 0, stream>>>(x, hb, ln1w + l * DIM, ln1b + l * DIM);
        gemm_bf_kernel<0, true, false><<<dim3(32, 18), 256, 0, stream>>>(
            hb, wqkv_t, nullptr, qkv, NTOK, QKVD, DIM);
        attn_kernel<<<dim3(16, NHEAD, 4), 256, 0, stream>>>(qkv, qkv + DIM, qkv + 2 * DIM, ao);
        gemm_bf_kernel<1, false, false><<<dim3(32, 6), 256, 0, stream>>>(
            ao, wo_t, x, x, NTOK, DIM, DIM);
        ln_kernel<<<NTOK, 256, 0, stream>>>(x, hb, ln2w + l * DIM, ln2b + l * DIM);
        gemm_bf_kernel<2, true, false><<<dim3(32, 24), 256, 0, stream>>>(
            hb, fc1_t, nullptr, u, NTOK, DFF_, DIM);
        gemm_bf_kernel<1, false, false><<<dim3(32, 6), 256, 0, stream>>>(
            u, fc2_t, x, x, NTOK, DIM, DFF_);
    }

    ln_kernel<<<NTOK, 256, 0, stream>>>(x, hb, lnfw, lnfb);
    // tied head: logits = h @ wte^T ; wteb is bf16 [VPAD, D] (rows >= V zero)
    gemm_bf_kernel<0, false, true><<<dim3(32, 393), 256, 0, stream>>>(
        hb, wteb, nullptr, out, NTOK, VOCAB, DIM);
}